// Round 1
// baseline (254.670 us; speedup 1.0000x reference)
//
#include <hip/hip_runtime.h>
#include <stdint.h>

// Problem constants (fixed by the reference's setup_inputs)
#define NB 131072
#define ND 384
#define NA 1024
#define NH 512
#define BM 64      // rows of x per block
#define CAP 1024   // sparse correction-pair capacity per block

using bf16x8 = __attribute__((ext_vector_type(8))) __bf16;
using f32x16 = __attribute__((ext_vector_type(16))) float;
using f32x4  = __attribute__((ext_vector_type(4))) float;
using i32x4  = __attribute__((ext_vector_type(4))) int;

__device__ __forceinline__ unsigned short f2bf(float f) {
  unsigned int u = __float_as_uint(f);
  u += 0x7fffu + ((u >> 16) & 1u);   // round-to-nearest-even
  return (unsigned short)(u >> 16);
}

// ---------------- prep: normalize anchors -> bf16, pre-swizzled into MFMA
// B-fragment order for v_mfma_f32_32x32x16_bf16:
//   B[k][n]: lane l holds an[cb*32 + (l&31)][s*16 + (l>>5)*8 + j], j=0..7
// stored so that a wave's (cb,s) load is 64 lanes * 16B contiguous.
__global__ void prep_anchors(const float* __restrict__ anchors,
                             short* __restrict__ an_swz) {
  const int a = blockIdx.x;    // anchor row
  const int l = threadIdx.x;   // 64 lanes
  float v[6];
  float ss = 0.f;
#pragma unroll
  for (int e = 0; e < 6; ++e) {
    v[e] = anchors[a * ND + l + 64 * e];
    ss += v[e] * v[e];
  }
#pragma unroll
  for (int off = 32; off >= 1; off >>= 1) ss += __shfl_xor(ss, off);
  const float rn = 1.0f / fmaxf(sqrtf(ss), 1e-12f);
  const int cb = a >> 5;
#pragma unroll
  for (int e = 0; e < 6; ++e) {
    const int k = l + 64 * e;
    const int s = k >> 4, half = (k >> 3) & 1, j = k & 7;
    const int l2 = (a & 31) + 32 * half;
    an_swz[(cb * 24 + s) * 512 + l2 * 8 + j] = (short)f2bf(v[e] * rn);
  }
}

// ---------------- prep: Vsum[h] = sum_a values[a][h] (two-stage, deterministic)
__global__ void vsum_part(const float* __restrict__ values,
                          float* __restrict__ partial) {
  const int jb = blockIdx.x, t = threadIdx.x;
  for (int hh = t; hh < NH; hh += 256) {
    float s = 0.f;
    for (int a2 = 0; a2 < 32; ++a2) s += values[(jb * 32 + a2) * NH + hh];
    partial[jb * NH + hh] = s;
  }
}

__global__ void vsum_final(const float* __restrict__ partial,
                           float* __restrict__ vsum) {
  const int t = threadIdx.x;
  float s = 0.f;
  for (int j = 0; j < 32; ++j) s += partial[j * NH + t];
  vsum[t] = s;
}

// ---------------- main fused kernel
// grid = NB/BM blocks, 512 threads (8 waves). Per block:
//   stage x[64][384] fp32->bf16 into XOR-swizzled LDS + row norms
//   wave w handles anchor col-block cb = chunk*8+w (32 cols), K=384 via 24 MFMA steps
//   quantize -> write qsims; rare nonzero bins go to a sparse pair list
//   epilogue: out[b,h] = (Vsum[h] + sum_pairs delta*v[a][h]) / (1024 + sum delta)
__global__ __launch_bounds__(512, 2) void fused_main(
    const float* __restrict__ x, const short* __restrict__ an_swz,
    const float* __restrict__ values, const float* __restrict__ vsum,
    float* __restrict__ out, float* __restrict__ qsims) {
  __shared__ unsigned char xbuf[BM * 768];  // bf16 [64][384], XOR-swizzled
  __shared__ float rsc[BM];
  __shared__ float vsum_s[NH];
  __shared__ float denom_add[BM];
  __shared__ int npairs;
  __shared__ int pr_ra[CAP];
  __shared__ float pr_d[CAP];

  const int t = threadIdx.x;
  const long rowbase = (long)blockIdx.x * BM;

  if (t < BM) denom_add[t] = 0.f;
  if (t == 0) npairs = 0;
  vsum_s[t] = vsum[t];

  // ---- stage x tile
  {
    const int r = t >> 3, c = t & 7;  // 8 threads per row
    const float* xrow = x + (rowbase + r) * ND;
    float ss = 0.f;
#pragma unroll
    for (int j = 0; j < 6; ++j) {
      const int col0 = c * 8 + j * 64;
      f32x4 v0 = *reinterpret_cast<const f32x4*>(xrow + col0);
      f32x4 v1 = *reinterpret_cast<const f32x4*>(xrow + col0 + 4);
      ss += v0[0] * v0[0] + v0[1] * v0[1] + v0[2] * v0[2] + v0[3] * v0[3];
      ss += v1[0] * v1[0] + v1[1] * v1[1] + v1[2] * v1[2] + v1[3] * v1[3];
      union { unsigned short us[8]; i32x4 q; } pk;
#pragma unroll
      for (int e = 0; e < 4; ++e) {
        pk.us[e] = f2bf(v0[e]);
        pk.us[4 + e] = f2bf(v1[e]);
      }
      // row*768 has bits 0..7 == 0, col0*2 < 768 -> XOR on bits 4..6 is safe
      *reinterpret_cast<i32x4*>(
          xbuf + ((r * 768 + col0 * 2) ^ ((r & 7) << 4))) = pk.q;
    }
    ss += __shfl_xor(ss, 1);
    ss += __shfl_xor(ss, 2);
    ss += __shfl_xor(ss, 4);
    if (c == 0) {
      const float scale = 1.0f / sqrtf((float)ND);
      rsc[r] = scale / fmaxf(sqrtf(ss), 1e-12f);
    }
  }
  __syncthreads();

  const int w = t >> 6, l = t & 63;
  const int lc = l & 31, lh = l >> 5;
  const int swz = (lc & 7) << 4;
  const unsigned char* arow0 = xbuf + 768 * lc;
  const unsigned char* arow1 = xbuf + 768 * (lc + 32);

  for (int chunk = 0; chunk < 4; ++chunk) {
    const int cb = chunk * 8 + w;  // global 32-col anchor block, 0..31
    f32x16 acc0 = {0, 0, 0, 0, 0, 0, 0, 0, 0, 0, 0, 0, 0, 0, 0, 0};
    f32x16 acc1 = {0, 0, 0, 0, 0, 0, 0, 0, 0, 0, 0, 0, 0, 0, 0, 0};
    const short* bptr = an_swz + (cb * 24) * 512 + l * 8;
#pragma unroll
    for (int s = 0; s < 24; ++s) {
      const int off = (s * 32 + lh * 16) ^ swz;
      bf16x8 a0 = *reinterpret_cast<const bf16x8*>(arow0 + off);
      bf16x8 a1 = *reinterpret_cast<const bf16x8*>(arow1 + off);
      bf16x8 bb = *reinterpret_cast<const bf16x8*>(bptr + s * 512);
      acc0 = __builtin_amdgcn_mfma_f32_32x32x16_bf16(a0, bb, acc0, 0, 0, 0);
      acc1 = __builtin_amdgcn_mfma_f32_32x32x16_bf16(a1, bb, acc1, 0, 0, 0);
    }

    // quantize + write qsims; C/D layout: col=lane&31, row=(i&3)+8*(i>>2)+4*(lane>>5)
    const int col = cb * 32 + lc;
    int nz = 0;
#pragma unroll
    for (int m = 0; m < 2; ++m) {
#pragma unroll
      for (int i = 0; i < 16; ++i) {
        const int rl = m * 32 + (i & 3) + 8 * (i >> 2) + 4 * lh;
        const float sval = (m ? acc1[i] : acc0[i]) * rsc[rl];
        const float qv = rintf(sval * 20.0f) * 0.05f;
        qsims[(rowbase + rl) * NA + col] = qv;
        nz |= (qv != 0.0f) ? 1 : 0;
      }
    }
    if (__ballot(nz != 0)) {  // rare: some sims crossed a bin boundary
#pragma unroll
      for (int m = 0; m < 2; ++m) {
#pragma unroll
        for (int i = 0; i < 16; ++i) {
          const int rl = m * 32 + (i & 3) + 8 * (i >> 2) + 4 * lh;
          const float sval = (m ? acc1[i] : acc0[i]) * rsc[rl];
          const float qv = rintf(sval * 20.0f) * 0.05f;
          if (qv != 0.0f) {
            const float dl = expf(qv) - 1.0f;
            const int idx = atomicAdd(&npairs, 1);
            if (idx < CAP) {
              pr_ra[idx] = (rl << 16) | col;
              pr_d[idx] = dl;
            }
            atomicAdd(&denom_add[rl], dl);
          }
        }
      }
    }
  }
  __syncthreads();

  // ---- epilogue: output rows
  const int np = npairs;
  const int hq = (t & 127) * 4;
  const int rb = t >> 7;
  if (np <= CAP) {
    for (int it = 0; it < 16; ++it) {
      const int r = it * 4 + rb;
      const float inv = 1.0f / (1024.0f + denom_add[r]);
      f32x4 o = *reinterpret_cast<const f32x4*>(&vsum_s[hq]);
      for (int p = 0; p < np; ++p) {
        const int ra = pr_ra[p];
        if ((ra >> 16) == r) {
          const float dl = pr_d[p];
          const float* vrow = values + (ra & 0xffff) * NH + hq;
          o[0] += dl * vrow[0];
          o[1] += dl * vrow[1];
          o[2] += dl * vrow[2];
          o[3] += dl * vrow[3];
        }
      }
      o[0] *= inv; o[1] *= inv; o[2] *= inv; o[3] *= inv;
      *reinterpret_cast<f32x4*>(out + (rowbase + r) * NH + hq) = o;
    }
  } else {
    // fully-general fallback (never expected): recompute from qsims
    for (int it = 0; it < 16; ++it) {
      const int r = it * 4 + rb;
      const float* qrow = qsims + (rowbase + r) * NA;
      float den = 0.f;
      f32x4 o = {0.f, 0.f, 0.f, 0.f};
      for (int a = 0; a < NA; ++a) {
        const float e = expf(qrow[a]);
        den += e;
        const float* vrow = values + a * NH + hq;
        o[0] += e * vrow[0];
        o[1] += e * vrow[1];
        o[2] += e * vrow[2];
        o[3] += e * vrow[3];
      }
      const float inv = 1.0f / den;
      o[0] *= inv; o[1] *= inv; o[2] *= inv; o[3] *= inv;
      *reinterpret_cast<f32x4*>(out + (rowbase + r) * NH + hq) = o;
    }
  }
}

extern "C" void kernel_launch(void* const* d_in, const int* in_sizes, int n_in,
                              void* d_out, int out_size, void* d_ws,
                              size_t ws_size, hipStream_t stream) {
  const float* x = (const float*)d_in[0];
  const float* anchors = (const float*)d_in[1];
  const float* values = (const float*)d_in[2];
  float* out = (float*)d_out;                        // [NB, NH]
  float* qsims = out + (size_t)NB * NH;              // [NB, NA]

  // workspace layout
  short* an_swz = (short*)d_ws;                      // 768 KB
  float* vsum = (float*)((char*)d_ws + 786432);      // 2 KB
  float* partial = (float*)((char*)d_ws + 786432 + 2048);  // 64 KB

  prep_anchors<<<NA, 64, 0, stream>>>(anchors, an_swz);
  vsum_part<<<32, 256, 0, stream>>>(values, partial);
  vsum_final<<<1, 512, 0, stream>>>(partial, vsum);
  fused_main<<<NB / BM, 512, 0, stream>>>(x, an_swz, values, vsum, out, qsims);
}